// Round 1
// baseline (5268.942 us; speedup 1.0000x reference)
//
#include <hip/hip_runtime.h>
#include <cstdint>
#include <cstddef>

#define M_TOK 65536
#define DIM   640
#define LAT   2560
#define KSEL  32

// ---------------------------------------------------------------------------
// K0: transpose W_dec [640][2560] -> WdT [2560][640] so decode gathers rows.
// ---------------------------------------------------------------------------
__global__ __launch_bounds__(256) void k_transpose(const float* __restrict__ W,
                                                   float* __restrict__ WT) {
  __shared__ float tile[32][33];  // +1 pad breaks bank conflicts
  const int c0 = blockIdx.x * 32;  // latent dim (2560/32 = 80)
  const int r0 = blockIdx.y * 32;  // input dim  (640/32  = 20)
  const int tx = threadIdx.x & 31;
  const int ty = threadIdx.x >> 5;  // 0..7
#pragma unroll
  for (int i = 0; i < 32; i += 8) {
    tile[ty + i][tx] = W[(r0 + ty + i) * LAT + c0 + tx];
  }
  __syncthreads();
#pragma unroll
  for (int i = 0; i < 32; i += 8) {
    WT[(c0 + ty + i) * DIM + r0 + tx] = tile[tx][ty + i];
  }
}

// ---------------------------------------------------------------------------
// K1: encode SGEMM  Lat[M,LAT] = X[M,640] @ W_enc[LAT,640]^T + b_enc
// fp32 VALU GEMM. Block tile 128(M) x 256(N), BK=16, 256 threads,
// per-thread micro-tile 8x16 with stride-16 sub-tiling (conflict-free LDS).
// ---------------------------------------------------------------------------
__global__ __launch_bounds__(256, 2) void k_encode(
    const float* __restrict__ X, const float* __restrict__ W,
    const float* __restrict__ be, float* __restrict__ Lat) {
  __shared__ float4 As4[4 * 128];   // [kq][m], K-quad major, 8 KB
  __shared__ float4 Bs4[4 * 256];   // [kq][n], 16 KB
  const int tid = threadIdx.x;
  const int bn0 = blockIdx.x * 256;  // grid.x = 10  (N fastest for LLC reuse of x panels)
  const int bm0 = blockIdx.y * 128;  // grid.y = 512
  const int tm = tid >> 4;  // 0..15 -> m = tm + mm*16
  const int tn = tid & 15;  // 0..15 -> n = tn + nn*16

  float acc[8][16];
#pragma unroll
  for (int i = 0; i < 8; ++i)
#pragma unroll
    for (int j = 0; j < 16; ++j) acc[i][j] = 0.f;

  for (int kb = 0; kb < 640; kb += 16) {
    // stage A tile: 128 m x 4 kquads = 512 float4, 2 per thread, coalesced
#pragma unroll
    for (int i = 0; i < 2; ++i) {
      int f = i * 256 + tid;
      int m = f >> 2, kq = f & 3;
      As4[kq * 128 + m] = *(const float4*)(X + (bm0 + m) * 640 + kb + kq * 4);
    }
    // stage B tile: 256 n x 4 kquads = 1024 float4, 4 per thread
#pragma unroll
    for (int i = 0; i < 4; ++i) {
      int f = i * 256 + tid;
      int n = f >> 2, kq = f & 3;
      Bs4[kq * 256 + n] = *(const float4*)(W + (bn0 + n) * 640 + kb + kq * 4);
    }
    __syncthreads();
#pragma unroll
    for (int kq = 0; kq < 4; ++kq) {
      float4 a[8];
#pragma unroll
      for (int mm = 0; mm < 8; ++mm) a[mm] = As4[kq * 128 + mm * 16 + tm];
#pragma unroll
      for (int nc = 0; nc < 4; ++nc) {  // b in chunks of 4 to bound VGPRs
        float4 b[4];
#pragma unroll
        for (int bb = 0; bb < 4; ++bb)
          b[bb] = Bs4[kq * 256 + (nc * 4 + bb) * 16 + tn];
#pragma unroll
        for (int mm = 0; mm < 8; ++mm)
#pragma unroll
          for (int bb = 0; bb < 4; ++bb) {
            float4 av = a[mm], bv = b[bb];
            float t = acc[mm][nc * 4 + bb];
            t += av.x * bv.x;
            t += av.y * bv.y;
            t += av.z * bv.z;
            t += av.w * bv.w;
            acc[mm][nc * 4 + bb] = t;
          }
      }
    }
    __syncthreads();
  }
  // epilogue: + b_enc, store (16-lane contiguous groups)
#pragma unroll
  for (int nn = 0; nn < 16; ++nn) {
    float bias = be[bn0 + nn * 16 + tn];
#pragma unroll
    for (int mm = 0; mm < 8; ++mm) {
      Lat[(bm0 + mm * 16 + tm) * LAT + bn0 + nn * 16 + tn] = acc[mm][nn] + bias;
    }
  }
}

// ---------------------------------------------------------------------------
// K2: per-row exact top-32 (tie-break: lower index first, matching jax),
// sparsify row in place, emit compact (idx,val) for decode.
// Strategy: candidate filter at mu+1.8*sigma (~92 cands expected), bitonic
// sort of 44-bit keys (orderable-float<<12 | (4095-idx)), fallback rungs.
// ---------------------------------------------------------------------------
__device__ inline unsigned int ordf(float f) {
  unsigned int u = __float_as_uint(f);
  return (u & 0x80000000u) ? ~u : (u | 0x80000000u);
}
__device__ inline float iordf(unsigned int o) {
  unsigned int u = (o & 0x80000000u) ? (o ^ 0x80000000u) : ~o;
  return __uint_as_float(u);
}

__global__ __launch_bounds__(256) void k_topk(float* __restrict__ Lat,
                                              float* __restrict__ topv,
                                              int* __restrict__ topi) {
  const int row = blockIdx.x;
  const int tid = threadIdx.x;
  float* Rp = Lat + (size_t)row * LAT;

  __shared__ unsigned long long cand[4096];  // 32 KB; reused as out-row later
  __shared__ float s_red[8];
  __shared__ int s_cnt;
  __shared__ float s_stats[2];
  __shared__ int s_selIdx[KSEL];
  __shared__ float s_selVal[KSEL];

  // load row (10 values/thread, coalesced) + moments
  float v[10];
  float s = 0.f, ss = 0.f;
#pragma unroll
  for (int j = 0; j < 10; ++j) {
    v[j] = Rp[tid + j * 256];
    s += v[j];
    ss += v[j] * v[j];
  }
#pragma unroll
  for (int off = 32; off > 0; off >>= 1) {
    s += __shfl_down(s, off);
    ss += __shfl_down(ss, off);
  }
  const int wave = tid >> 6, lane = tid & 63;
  if (lane == 0) {
    s_red[wave] = s;
    s_red[4 + wave] = ss;
  }
  if (tid == 0) s_cnt = 0;
  __syncthreads();
  if (tid == 0) {
    float S = s_red[0] + s_red[1] + s_red[2] + s_red[3];
    float SS = s_red[4] + s_red[5] + s_red[6] + s_red[7];
    float mean = S * (1.f / LAT);
    float var = SS * (1.f / LAT) - mean * mean;
    s_stats[0] = mean;
    s_stats[1] = sqrtf(fmaxf(var, 0.f));
  }
  __syncthreads();
  const float mean = s_stats[0], sig = s_stats[1];

  // threshold ladder: rung 0 covers ~all rows; rung 2 (all values) is a
  // guaranteed-correct last resort (cnt=2560 <= 4096 slots, never overflows)
  int cnt = 0;
  for (int rung = 0; rung < 3; ++rung) {
    float t = (rung == 0) ? (mean + 1.8f * sig)
            : (rung == 1) ? (mean + 0.5f * sig)
                          : -3.4e38f;
    if (rung > 0) {
      if (tid == 0) s_cnt = 0;
    }
    __syncthreads();
#pragma unroll
    for (int j = 0; j < 10; ++j) {
      if (v[j] > t) {
        int p = atomicAdd(&s_cnt, 1);
        int idx = tid + j * 256;
        unsigned long long key =
            ((unsigned long long)ordf(v[j]) << 12) | (unsigned long long)(4095 - idx);
        cand[p] = ~key;  // inverted key: ascending sort == value desc, idx asc
      }
    }
    __syncthreads();
    cnt = s_cnt;  // block-uniform
    if (cnt >= KSEL) break;
  }

  // pad to pow2 and bitonic-sort ascending (inverted keys)
  int P = 64;
  while (P < cnt) P <<= 1;  // <= 4096
  for (int i = cnt + tid; i < P; i += 256) cand[i] = ~0ULL;
  __syncthreads();
  for (int k = 2; k <= P; k <<= 1) {
    for (int j = k >> 1; j > 0; j >>= 1) {
      for (int i = tid; i < P; i += 256) {
        int ixj = i ^ j;
        if (ixj > i) {
          unsigned long long a = cand[i], b = cand[ixj];
          bool up = ((i & k) == 0);
          if ((a > b) == up) {
            cand[i] = b;
            cand[ixj] = a;
          }
        }
      }
      __syncthreads();
    }
  }

  // extract top-32, write compact lists
  if (tid < KSEL) {
    unsigned long long key = ~cand[tid];
    unsigned int ou = (unsigned int)(key >> 12);
    int idx = 4095 - (int)(key & 0xFFFULL);
    float val = iordf(ou);
    s_selIdx[tid] = idx;
    s_selVal[tid] = val;
    topv[row * KSEL + tid] = val;
    topi[row * KSEL + tid] = idx;
  }
  __syncthreads();

  // sparsify row in place: zeros + 32 selected values
  float* outrow = (float*)cand;
#pragma unroll
  for (int j = 0; j < 10; ++j) outrow[tid + j * 256] = 0.f;
  __syncthreads();
  if (tid < KSEL) outrow[s_selIdx[tid]] = s_selVal[tid];
  __syncthreads();
#pragma unroll
  for (int j = 0; j < 10; ++j) Rp[tid + j * 256] = outrow[tid + j * 256];
}

// ---------------------------------------------------------------------------
// K3: decode  recon[row,:] = sum_j topv[j] * WdT[topi[j],:] + b_dec
// Coalesced gathers; WdT (6.5 MB) stays L2/LLC resident.
// ---------------------------------------------------------------------------
__global__ __launch_bounds__(256) void k_decode(const float* __restrict__ topv,
                                                const int* __restrict__ topi,
                                                const float* __restrict__ WdT,
                                                const float* __restrict__ bd,
                                                float* __restrict__ recon) {
  const int row = blockIdx.x;
  const int tid = threadIdx.x;
  __shared__ float sv[KSEL];
  __shared__ int si[KSEL];
  if (tid < KSEL) {
    sv[tid] = topv[row * KSEL + tid];
    si[tid] = topi[row * KSEL + tid];
  }
  __syncthreads();
  for (int d = tid; d < DIM; d += 256) {
    float acc = bd[d];
#pragma unroll
    for (int j = 0; j < KSEL; ++j) acc += sv[j] * WdT[si[j] * DIM + d];
    recon[(size_t)row * DIM + d] = acc;
  }
}

// ---------------------------------------------------------------------------
extern "C" void kernel_launch(void* const* d_in, const int* in_sizes, int n_in,
                              void* d_out, int out_size, void* d_ws, size_t ws_size,
                              hipStream_t stream) {
  const float* x     = (const float*)d_in[0];
  const float* W_enc = (const float*)d_in[1];
  const float* b_enc = (const float*)d_in[2];
  const float* W_dec = (const float*)d_in[3];
  const float* b_dec = (const float*)d_in[4];

  float* out    = (float*)d_out;
  float* recon  = out;                          // 65536*640
  float* sparse = out + (size_t)M_TOK * DIM;    // 65536*2560 (latents live here too)

  float* WdT  = (float*)d_ws;                   // 2560*640
  float* topv = WdT + (size_t)LAT * DIM;        // 65536*32
  int*   topi = (int*)(topv + (size_t)M_TOK * KSEL);

  k_transpose<<<dim3(LAT / 32, DIM / 32), 256, 0, stream>>>(W_dec, WdT);
  k_encode<<<dim3(LAT / 256, M_TOK / 128), 256, 0, stream>>>(x, W_enc, b_enc, sparse);
  k_topk<<<M_TOK, 256, 0, stream>>>(sparse, topv, topi);
  k_decode<<<M_TOK, 256, 0, stream>>>(topv, topi, WdT, b_dec, recon);
}

// Round 2
// 4030.084 us; speedup vs baseline: 1.3074x; 1.3074x over previous
//
#include <hip/hip_runtime.h>
#include <cstdint>
#include <cstddef>

#define M_TOK 65536
#define DIM   640
#define LAT   2560
#define KSEL  32

// ---------------------------------------------------------------------------
// K0: transpose W_dec [640][2560] -> WdT [2560][640] so decode gathers rows.
// ---------------------------------------------------------------------------
__global__ __launch_bounds__(256) void k_transpose(const float* __restrict__ W,
                                                   float* __restrict__ WT) {
  __shared__ float tile[32][33];
  const int c0 = blockIdx.x * 32;
  const int r0 = blockIdx.y * 32;
  const int tx = threadIdx.x & 31;
  const int ty = threadIdx.x >> 5;
#pragma unroll
  for (int i = 0; i < 32; i += 8) {
    tile[ty + i][tx] = W[(r0 + ty + i) * LAT + c0 + tx];
  }
  __syncthreads();
#pragma unroll
  for (int i = 0; i < 32; i += 8) {
    WT[(c0 + ty + i) * DIM + r0 + tx] = tile[tx][ty + i];
  }
}

// ---------------------------------------------------------------------------
// K1: encode SGEMM  Lat[M,LAT] = X[M,640] @ W_enc[LAT,640]^T + b_enc
// fp32 VALU GEMM. Block tile 128x128, BK=16, 256 threads, micro-tile 8x8,
// stride-16 sub-tiling. acc=64 regs + a=32 + b-chunk=16 -> ~140 live VGPRs,
// no spills (round-1 spilled: acc[8][16]=128 regs vs VGPR_Count=128 ->
// 1 GB of scratch traffic). Accumulation order per latent is bit-identical
// to round 1 (k-quads ascending, x,y,z,w within quad).
// ---------------------------------------------------------------------------
__global__ __launch_bounds__(256, 3) void k_encode(
    const float* __restrict__ X, const float* __restrict__ W,
    const float* __restrict__ be, float* __restrict__ Lat) {
  __shared__ float4 As4[4 * 128];   // [kq][m], 8 KB
  __shared__ float4 Bs4[4 * 128];   // [kq][n], 8 KB
  const int tid = threadIdx.x;
  const int bn0 = blockIdx.x * 128;  // grid.x = 20
  const int bm0 = blockIdx.y * 128;  // grid.y = 512
  const int tm = tid >> 4;  // 0..15 -> m = tm + mm*16
  const int tn = tid & 15;  // 0..15 -> n = tn + nn*16

  float acc[8][8];
#pragma unroll
  for (int i = 0; i < 8; ++i)
#pragma unroll
    for (int j = 0; j < 8; ++j) acc[i][j] = 0.f;

  for (int kb = 0; kb < 640; kb += 16) {
    // stage A+B tiles: 512 float4 each, 2 per thread, kq-fastest (64B segments)
#pragma unroll
    for (int i = 0; i < 2; ++i) {
      int f = i * 256 + tid;
      int m = f >> 2, kq = f & 3;
      As4[kq * 128 + m] = *(const float4*)(X + (size_t)(bm0 + m) * 640 + kb + kq * 4);
      Bs4[kq * 128 + m] = *(const float4*)(W + (size_t)(bn0 + m) * 640 + kb + kq * 4);
    }
    __syncthreads();
#pragma unroll
    for (int kq = 0; kq < 4; ++kq) {
      float4 a[8];
#pragma unroll
      for (int mm = 0; mm < 8; ++mm) a[mm] = As4[kq * 128 + mm * 16 + tm];
#pragma unroll
      for (int nc = 0; nc < 2; ++nc) {  // b in chunks of 4 to bound VGPRs
        float4 b[4];
#pragma unroll
        for (int bb = 0; bb < 4; ++bb)
          b[bb] = Bs4[kq * 128 + (nc * 4 + bb) * 16 + tn];
#pragma unroll
        for (int mm = 0; mm < 8; ++mm)
#pragma unroll
          for (int bb = 0; bb < 4; ++bb) {
            float4 av = a[mm], bv = b[bb];
            float t = acc[mm][nc * 4 + bb];
            t += av.x * bv.x;
            t += av.y * bv.y;
            t += av.z * bv.z;
            t += av.w * bv.w;
            acc[mm][nc * 4 + bb] = t;
          }
      }
    }
    __syncthreads();
  }
  // epilogue: + b_enc, store (16-lane contiguous groups)
#pragma unroll
  for (int nn = 0; nn < 8; ++nn) {
    float bias = be[bn0 + nn * 16 + tn];
#pragma unroll
    for (int mm = 0; mm < 8; ++mm) {
      Lat[(size_t)(bm0 + mm * 16 + tm) * LAT + bn0 + nn * 16 + tn] =
          acc[mm][nn] + bias;
    }
  }
}

// ---------------------------------------------------------------------------
// K2: per-row exact top-32 (tie-break: lower index first, matching jax),
// sparsify row in place, emit compact (idx,val) for decode.
// Ballot-compaction (1 LDS atomic per wave per chunk, not per element).
// ---------------------------------------------------------------------------
__device__ inline unsigned int ordf(float f) {
  unsigned int u = __float_as_uint(f);
  return (u & 0x80000000u) ? ~u : (u | 0x80000000u);
}
__device__ inline float iordf(unsigned int o) {
  unsigned int u = (o & 0x80000000u) ? (o ^ 0x80000000u) : ~o;
  return __uint_as_float(u);
}

__global__ __launch_bounds__(256) void k_topk(float* __restrict__ Lat,
                                              float* __restrict__ topv,
                                              int* __restrict__ topi) {
  const int row = blockIdx.x;
  const int tid = threadIdx.x;
  float* Rp = Lat + (size_t)row * LAT;

  __shared__ unsigned long long cand[4096];  // 32 KB; reused as out-row later
  __shared__ float s_red[8];
  __shared__ int s_cnt;
  __shared__ float s_stats[2];
  __shared__ int s_selIdx[KSEL];
  __shared__ float s_selVal[KSEL];

  // load row (10 values/thread, coalesced) + moments
  float v[10];
  float s = 0.f, ss = 0.f;
#pragma unroll
  for (int j = 0; j < 10; ++j) {
    v[j] = Rp[tid + j * 256];
    s += v[j];
    ss += v[j] * v[j];
  }
#pragma unroll
  for (int off = 32; off > 0; off >>= 1) {
    s += __shfl_down(s, off);
    ss += __shfl_down(ss, off);
  }
  const int wave = tid >> 6, lane = tid & 63;
  if (lane == 0) {
    s_red[wave] = s;
    s_red[4 + wave] = ss;
  }
  if (tid == 0) s_cnt = 0;
  __syncthreads();
  if (tid == 0) {
    float S = s_red[0] + s_red[1] + s_red[2] + s_red[3];
    float SS = s_red[4] + s_red[5] + s_red[6] + s_red[7];
    float mean = S * (1.f / LAT);
    float var = SS * (1.f / LAT) - mean * mean;
    s_stats[0] = mean;
    s_stats[1] = sqrtf(fmaxf(var, 0.f));
  }
  __syncthreads();
  const float mean = s_stats[0], sig = s_stats[1];

  // threshold ladder: rung 0 (~58 cands expected) covers ~all rows; rung 2
  // (all 2560 values) is a guaranteed-correct last resort.
  int cnt = 0;
  for (int rung = 0; rung < 3; ++rung) {
    float t = (rung == 0) ? (mean + 2.0f * sig)
            : (rung == 1) ? (mean + 1.0f * sig)
                          : -3.4e38f;
    if (rung > 0) {
      if (tid == 0) s_cnt = 0;
    }
    __syncthreads();
#pragma unroll
    for (int j = 0; j < 10; ++j) {
      bool pred = v[j] > t;
      unsigned long long mask = __ballot(pred);
      int nset = __popcll(mask);
      int base = 0;
      if (lane == 0 && nset) base = atomicAdd(&s_cnt, nset);
      base = __shfl(base, 0);
      if (pred) {
        int off = __popcll(mask & ((1ULL << lane) - 1ULL));
        int idx = tid + j * 256;
        unsigned long long key =
            ((unsigned long long)ordf(v[j]) << 12) | (unsigned long long)(4095 - idx);
        cand[base + off] = ~key;  // inverted: ascending sort == val desc, idx asc
      }
    }
    __syncthreads();
    cnt = s_cnt;  // block-uniform
    if (cnt >= KSEL) break;
  }

  // pad to pow2 and bitonic-sort ascending (inverted keys)
  int P = 64;
  while (P < cnt) P <<= 1;  // <= 4096
  for (int i = cnt + tid; i < P; i += 256) cand[i] = ~0ULL;
  __syncthreads();
  for (int k = 2; k <= P; k <<= 1) {
    for (int j = k >> 1; j > 0; j >>= 1) {
      for (int i = tid; i < P; i += 256) {
        int ixj = i ^ j;
        if (ixj > i) {
          unsigned long long a = cand[i], b = cand[ixj];
          bool up = ((i & k) == 0);
          if ((a > b) == up) {
            cand[i] = b;
            cand[ixj] = a;
          }
        }
      }
      __syncthreads();
    }
  }

  // extract top-32, write compact lists
  if (tid < KSEL) {
    unsigned long long key = ~cand[tid];
    unsigned int ou = (unsigned int)(key >> 12);
    int idx = 4095 - (int)(key & 0xFFFULL);
    float val = iordf(ou);
    s_selIdx[tid] = idx;
    s_selVal[tid] = val;
    topv[row * KSEL + tid] = val;
    topi[row * KSEL + tid] = idx;
  }
  __syncthreads();

  // sparsify row in place: zeros + 32 selected values
  float* outrow = (float*)cand;
#pragma unroll
  for (int j = 0; j < 10; ++j) outrow[tid + j * 256] = 0.f;
  __syncthreads();
  if (tid < KSEL) outrow[s_selIdx[tid]] = s_selVal[tid];
  __syncthreads();
#pragma unroll
  for (int j = 0; j < 10; ++j) Rp[tid + j * 256] = outrow[tid + j * 256];
}

// ---------------------------------------------------------------------------
// K3: decode  recon[row,:] = sum_j topv[j] * WdT[topi[j],:] + b_dec
// float4 gathers, 8 rows per block; WdT (6.5 MB) stays L2/LLC resident.
// ---------------------------------------------------------------------------
__global__ __launch_bounds__(256) void k_decode(const float* __restrict__ topv,
                                                const int* __restrict__ topi,
                                                const float* __restrict__ WdT,
                                                const float* __restrict__ bd,
                                                float* __restrict__ recon) {
  const int rb = blockIdx.x;  // 8 rows per block
  const int tid = threadIdx.x;
  __shared__ float sv[8][KSEL];
  __shared__ int si[8][KSEL];
  {
    int r = tid >> 5, j = tid & 31;  // 256 = 8*32, one entry per thread
    sv[r][j] = topv[(rb * 8 + r) * KSEL + j];
    si[r][j] = topi[(rb * 8 + r) * KSEL + j];
  }
  __syncthreads();
  const float4* W4 = (const float4*)WdT;
  const float4* b4 = (const float4*)bd;
  float4* out4 = (float4*)recon;
#pragma unroll
  for (int it = 0; it < 5; ++it) {  // 8 rows * 160 float4 = 1280 = 5*256
    int flat = it * 256 + tid;
    int r = flat / 160, d = flat - r * 160;
    float4 acc = b4[d];
#pragma unroll
    for (int j = 0; j < KSEL; ++j) {
      float sc = sv[r][j];
      float4 w = W4[(size_t)si[r][j] * 160 + d];
      acc.x += sc * w.x;
      acc.y += sc * w.y;
      acc.z += sc * w.z;
      acc.w += sc * w.w;
    }
    out4[(size_t)(rb * 8 + r) * 160 + d] = acc;
  }
}

// ---------------------------------------------------------------------------
extern "C" void kernel_launch(void* const* d_in, const int* in_sizes, int n_in,
                              void* d_out, int out_size, void* d_ws, size_t ws_size,
                              hipStream_t stream) {
  const float* x     = (const float*)d_in[0];
  const float* W_enc = (const float*)d_in[1];
  const float* b_enc = (const float*)d_in[2];
  const float* W_dec = (const float*)d_in[3];
  const float* b_dec = (const float*)d_in[4];

  float* out    = (float*)d_out;
  float* recon  = out;                          // 65536*640
  float* sparse = out + (size_t)M_TOK * DIM;    // 65536*2560 (latents live here)

  float* WdT  = (float*)d_ws;                   // 2560*640
  float* topv = WdT + (size_t)LAT * DIM;        // 65536*32
  int*   topi = (int*)(topv + (size_t)M_TOK * KSEL);

  k_transpose<<<dim3(LAT / 32, DIM / 32), 256, 0, stream>>>(W_dec, WdT);
  k_encode<<<dim3(LAT / 128, M_TOK / 128), 256, 0, stream>>>(x, W_enc, b_enc, sparse);
  k_topk<<<M_TOK, 256, 0, stream>>>(sparse, topv, topi);
  k_decode<<<M_TOK / 8, 256, 0, stream>>>(topv, topi, WdT, b_dec, recon);
}